// Round 11
// baseline (91.494 us; speedup 1.0000x reference)
//
#include <hip/hip_runtime.h>
#include <math.h>

#define NTOK 16384
#define DDIM 4096
#define NEXP 64
#define TAU  2e-4f
#define WS_LO 262144   // short-offset of the lo-plane inside d_ws
#define NCW  16        // chunks per K-eighth (512 k / 32)

typedef short bf16x8 __attribute__((ext_vector_type(8)));
typedef float f32x4  __attribute__((ext_vector_type(4)));

__device__ __forceinline__ unsigned short bf16_rne(float f) {
  unsigned u = __float_as_uint(f);
  u += 0x7fffu + ((u >> 16) & 1u);
  return (unsigned short)(u >> 16);
}

__device__ __forceinline__ void split4(float4 v, uint2& hi, uint2& lo) {
  unsigned h0 = bf16_rne(v.x), h1 = bf16_rne(v.y), h2 = bf16_rne(v.z), h3 = bf16_rne(v.w);
  float r0 = v.x - __uint_as_float(h0 << 16);
  float r1 = v.y - __uint_as_float(h1 << 16);
  float r2 = v.z - __uint_as_float(h2 << 16);
  float r3 = v.w - __uint_as_float(h3 << 16);
  unsigned l0 = bf16_rne(r0), l1 = bf16_rne(r1), l2 = bf16_rne(r2), l3 = bf16_rne(r3);
  hi = make_uint2(h0 | (h1 << 16), h2 | (h3 << 16));
  lo = make_uint2(l0 | (l1 << 16), l2 | (l3 << 16));
}

__device__ __forceinline__ void split4v(f32x4 v, uint2& hi, uint2& lo) {
  unsigned h0 = bf16_rne(v[0]), h1 = bf16_rne(v[1]), h2 = bf16_rne(v[2]), h3 = bf16_rne(v[3]);
  float r0 = v[0] - __uint_as_float(h0 << 16);
  float r1 = v[1] - __uint_as_float(h1 << 16);
  float r2 = v[2] - __uint_as_float(h2 << 16);
  float r3 = v[3] - __uint_as_float(h3 << 16);
  unsigned l0 = bf16_rne(r0), l1 = bf16_rne(r1), l2 = bf16_rne(r2), l3 = bf16_rne(r3);
  hi = make_uint2(h0 | (h1 << 16), h2 | (h3 << 16));
  lo = make_uint2(l0 | (l1 << 16), l2 | (l3 << 16));
}

__device__ __forceinline__ bf16x8 mk8(uint2 a, uint2 b) {
  union { uint4 u; bf16x8 v; } t;
  t.u = make_uint4(a.x, a.y, b.x, b.y);
  return t.v;
}

__device__ __forceinline__ void gld_lds16(const float* g, char* l) {
  __builtin_amdgcn_global_load_lds((const __attribute__((address_space(1))) void*)g,
                                   (__attribute__((address_space(3))) void*)l,
                                   16, 0, 0);
}

__device__ __forceinline__ bool better(float va, int ia, float vb, int ib) {
  return (va > vb) || (va == vb && ia < ib);
}
__device__ __forceinline__ bool betterd(double va, int ia, double vb, int ib) {
  return (va > vb) || (va == vb && ia < ib);
}
#define CE(va, ia, vb, ib) { if (better(vb, ib, va, ia)) { float _tv = va; va = vb; vb = _tv; int _ti = ia; ia = ib; ib = _ti; } }

// ---- kernel 1: split W (fp32) into bf16 hi/lo, MFMA-fragment-linear, once ----
__global__ __launch_bounds__(256)
void presplit_w(const float* __restrict__ w, short* __restrict__ ws) {
  const int tid = blockIdx.x * 256 + threadIdx.x;  // 32768 threads
  const int e = tid >> 9;          // expert 0..63
  const int o = tid & 511;         // k-octet 0..511
  const int c = o >> 2, q = o & 3;
  const int l = (e & 15) + 16 * q;
  const int g = e >> 4;
  const float* src = w + (size_t)e * DDIM + o * 8;
  float4 v0 = *(const float4*)src;
  float4 v1 = *(const float4*)(src + 4);
  uint2 h0, s0, h1, s1;
  split4(v0, h0, s0);
  split4(v1, h1, s1);
  const int off = c * 2048 + g * 512 + l * 8;
  *(uint4*)(ws + off)         = make_uint4(h0.x, h0.y, h1.x, h1.y);
  *(uint4*)(ws + WS_LO + off) = make_uint4(s0.x, s0.y, s1.x, s1.y);
}

// ---- fp64 recompute for near-tie tokens (rare); executed by one full wave ----
__device__ __noinline__ void fixup_token(const float* __restrict__ x,
                                         const float* __restrict__ wgt,
                                         float* __restrict__ out_idx,
                                         float* __restrict__ out_wt,
                                         int tok, unsigned pk, int l) {
  const int e0 = pk & 255, e1 = (pk >> 8) & 255, e2 = (pk >> 16) & 255, e3 = (pk >> 24) & 255;
  const float* xr = x   + (size_t)tok * DDIM + l * 64;
  const float* w0 = wgt + (size_t)e0 * DDIM + l * 64;
  const float* w1 = wgt + (size_t)e1 * DDIM + l * 64;
  const float* w2 = wgt + (size_t)e2 * DDIM + l * 64;
  const float* w3 = wgt + (size_t)e3 * DDIM + l * 64;
  double s0 = 0.0, s1 = 0.0, s2 = 0.0, s3 = 0.0;
#pragma unroll 4
  for (int j = 0; j < 64; j += 4) {
    float4 xv = *(const float4*)(xr + j);
    float4 av = *(const float4*)(w0 + j);
    s0 = fma((double)xv.x, (double)av.x, s0); s0 = fma((double)xv.y, (double)av.y, s0);
    s0 = fma((double)xv.z, (double)av.z, s0); s0 = fma((double)xv.w, (double)av.w, s0);
    av = *(const float4*)(w1 + j);
    s1 = fma((double)xv.x, (double)av.x, s1); s1 = fma((double)xv.y, (double)av.y, s1);
    s1 = fma((double)xv.z, (double)av.z, s1); s1 = fma((double)xv.w, (double)av.w, s1);
    av = *(const float4*)(w2 + j);
    s2 = fma((double)xv.x, (double)av.x, s2); s2 = fma((double)xv.y, (double)av.y, s2);
    s2 = fma((double)xv.z, (double)av.z, s2); s2 = fma((double)xv.w, (double)av.w, s2);
    av = *(const float4*)(w3 + j);
    s3 = fma((double)xv.x, (double)av.x, s3); s3 = fma((double)xv.y, (double)av.y, s3);
    s3 = fma((double)xv.z, (double)av.z, s3); s3 = fma((double)xv.w, (double)av.w, s3);
  }
#pragma unroll
  for (int m = 1; m < 64; m <<= 1) {
    s0 += __shfl_xor(s0, m);
    s1 += __shfl_xor(s1, m);
    s2 += __shfl_xor(s2, m);
    s3 += __shfl_xor(s3, m);
  }
  if (l == 0) {
    double v0 = s0, v1 = s1, v2 = s2, v3 = s3;
    int i0 = e0, i1 = e1, i2 = e2, i3 = e3;
    if (betterd(v1, i1, v0, i0)) { double tv = v0; v0 = v1; v1 = tv; int ti = i0; i0 = i1; i1 = ti; }
    if (betterd(v3, i3, v2, i2)) { double tv = v2; v2 = v3; v3 = tv; int ti = i2; i2 = i3; i3 = ti; }
    if (betterd(v2, i2, v0, i0)) { double tv = v0; v0 = v2; v2 = tv; int ti = i0; i0 = i2; i2 = ti; }
    if (betterd(v3, i3, v1, i1)) { double tv = v1; v1 = v3; v3 = tv; int ti = i1; i1 = i3; i3 = ti; }
    if (betterd(v2, i2, v1, i1)) { double tv = v1; v1 = v2; v2 = tv; int ti = i1; i1 = i2; i2 = ti; }
    double ex = exp(v1 - v0);
    double den = 1.0 + ex;
    out_idx[tok * 2 + 0] = (float)i0;
    out_idx[tok * 2 + 1] = (float)i1;
    out_wt[tok * 2 + 0]  = (float)(1.0 / den);
    out_wt[tok * 2 + 1]  = (float)(ex / den);
  }
}

// ---- kernel 2: K-split x8, max waves/CU, barrier-free counted-vmcnt ----
// 512 blocks x 512 thr (8 waves = 8 K-eighths). Block = 32 tokens x 64 experts.
// Per wave per 32k-chunk: X 4 KB (2 token-tiles, gld_lds) + W 8 KB (8 b128, dbuf).
// LDS: 8 waves x 2 slots x 4 KB = 64 KB -> 2 blocks/CU; VGPR cap 3/SIMD (no spill).
__global__ __launch_bounds__(512, 3)
void router_main(const float* __restrict__ x, const float* __restrict__ wgt,
                 const short* __restrict__ ws, float* __restrict__ out) {
  __shared__ __align__(16) char ldsbuf[65536];

  const int u = threadIdx.x;
  const int l = u & 63;
  const int wid = u >> 6;          // K-eighth 0..7
  const int tokBase = blockIdx.x * 32;

  char* ring = ldsbuf + wid * 8192;   // 2 slots x 4096 B
  const unsigned ldsbase =
      (unsigned)(size_t)(__attribute__((address_space(3))) char*)&ldsbuf[0];
  const unsigned rbase = ldsbase + wid * 8192 + l * 16;

  // k-phase rotation across blocks (within this wave's 16 chunks)
  const int P = (blockIdx.x * 5) & 15;
#define PHYS(T) (((T) + P) & 15)

  // A-fragment sources per token-tile: lane l = row (l&15), k-oct (l>>4)*8
  const float* xA0 = x + (size_t)(tokBase +  0 + (l & 15)) * DDIM + wid * 512 + (l >> 4) * 8;
  const float* xB0 = xA0 + 4;
  const float* xA1 = x + (size_t)(tokBase + 16 + (l & 15)) * DDIM + wid * 512 + (l >> 4) * 8;
  const float* xB1 = xA1 + 4;

  const short* wch = ws + wid * 32768 + l * 8;

  f32x4 acc[2][4];   // [token-tile][expert-group], all indices compile-time
#pragma unroll
  for (int t2 = 0; t2 < 2; ++t2)
#pragma unroll
    for (int g = 0; g < 4; ++g) acc[t2][g] = (f32x4){0.f, 0.f, 0.f, 0.f};

  bf16x8 wset[2][8];

#define LDW(SET, T)                                                            \
  { const int cw_ = ((T) < NCW) ? (T) : NCW - 1;                               \
    const int cc_ = PHYS(cw_);                                                 \
    asm volatile("" ::: "memory");                                             \
    wset[SET][0] = *(const bf16x8*)(wch + cc_ * 2048 + 0 * 512);               \
    wset[SET][1] = *(const bf16x8*)(wch + WS_LO + cc_ * 2048 + 0 * 512);       \
    wset[SET][2] = *(const bf16x8*)(wch + cc_ * 2048 + 1 * 512);               \
    wset[SET][3] = *(const bf16x8*)(wch + WS_LO + cc_ * 2048 + 1 * 512);       \
    wset[SET][4] = *(const bf16x8*)(wch + cc_ * 2048 + 2 * 512);               \
    wset[SET][5] = *(const bf16x8*)(wch + WS_LO + cc_ * 2048 + 2 * 512);       \
    wset[SET][6] = *(const bf16x8*)(wch + cc_ * 2048 + 3 * 512);               \
    wset[SET][7] = *(const bf16x8*)(wch + WS_LO + cc_ * 2048 + 3 * 512);       \
    asm volatile("" ::: "memory"); }

#define XISSUE(T, SLOT)                                                        \
  { const int cx_ = ((T) < NCW) ? (T) : NCW - 1;                               \
    const int cp_ = PHYS(cx_) * 32;                                            \
    char* d_ = ring + (SLOT) * 4096;                                           \
    gld_lds16(xA0 + cp_, d_);                                                  \
    gld_lds16(xB0 + cp_, d_ + 1024);                                           \
    gld_lds16(xA1 + cp_, d_ + 2048);                                           \
    gld_lds16(xB1 + cp_, d_ + 3072); }

#define MM(T2, G, SET)                                                         \
  acc[T2][G] = __builtin_amdgcn_mfma_f32_16x16x32_bf16(ahi, wset[SET][2*(G)],   acc[T2][G], 0, 0, 0); \
  acc[T2][G] = __builtin_amdgcn_mfma_f32_16x16x32_bf16(ahi, wset[SET][2*(G)+1], acc[T2][G], 0, 0, 0); \
  acc[T2][G] = __builtin_amdgcn_mfma_f32_16x16x32_bf16(alo, wset[SET][2*(G)],   acc[T2][G], 0, 0, 0);

#define COMPT(T2, SET, F0, F1)                                                 \
  { uint2 h0_, s0_, h1_, s1_;                                                  \
    split4v(F0, h0_, s0_); split4v(F1, h1_, s1_);                              \
    bf16x8 ahi = mk8(h0_, h1_), alo = mk8(s0_, s1_);                           \
    MM(T2, 0, SET) MM(T2, 1, SET) MM(T2, 2, SET) MM(T2, 3, SET) }

// per step T: [vmcnt(12): X(T),W(T) landed; X(T+1) 4 + W(T+1) 8 airborne]
//             [4 ds_read] [lgkmcnt+sched_barrier] [issue X(T+2) into slot T&1]
//             [compute 2 tiles] [LDW W(T+2) into set T&1]  => 12 issues/step
#define STEP(T, SLOT, SET)                                                     \
  {                                                                            \
    asm volatile("s_waitcnt vmcnt(12)" ::: "memory");                          \
    f32x4 f0, f1, f2, f3;                                                      \
    { unsigned a_ = rbase + (SLOT) * 4096;                                     \
      asm volatile("ds_read_b128 %0, %2\n\tds_read_b128 %1, %2 offset:1024"    \
                   : "=&v"(f0), "=&v"(f1) : "v"(a_));                          \
      asm volatile("ds_read_b128 %0, %2 offset:2048\n\tds_read_b128 %1, %2 offset:3072" \
                   : "=&v"(f2), "=&v"(f3) : "v"(a_)); }                        \
    asm volatile("s_waitcnt lgkmcnt(0)" ::: "memory");                         \
    __builtin_amdgcn_sched_barrier(0);                                         \
    XISSUE((T) + 2, SLOT)                                                      \
    asm volatile("" ::: "memory");                                             \
    COMPT(0, SET, f0, f1)                                                      \
    COMPT(1, SET, f2, f3)                                                      \
    LDW(SET, (T) + 2)                                                          \
  }

  // prologue FIFO: X0(4), W0(8), X1(4), W1(8) = 24 outstanding
  XISSUE(0, 0)
  LDW(0, 0)
  XISSUE(1, 1)
  LDW(1, 1)

  for (int t = 0; t < NCW; t += 2) {
    STEP(t, 0, 0)
    STEP(t + 1, 1, 1)
  }

  // ---- combine K-eighths through LDS (aliased over the rings, 64 KB exactly) ----
  __syncthreads();   // drains vmcnt(0): all dead gld_lds landed; rings dead
  float* p = (float*)ldsbuf;
#define PIDX(KQ, T2, G, R) ((((((KQ) * 2 + (T2)) * 4 + (G)) * 4 + (R)) << 6) + l)
#pragma unroll
  for (int t2 = 0; t2 < 2; ++t2)
#pragma unroll
    for (int g = 0; g < 4; ++g)
#pragma unroll
      for (int r = 0; r < 4; ++r)
        p[PIDX(wid, t2, g, r)] = acc[t2][g][r];
  __syncthreads();

  float* out_idx = out;
  float* out_wt  = out + NTOK * 2;
  float* out_lg  = out + NTOK * 4;

  // wave `wid` handles (t2 = wid>>2, r = wid&3): tokens t2*16 + (l>>4)*4 + r
  {
    const int t2 = wid >> 2;
    const int r  = wid & 3;
    float v0 = 0.f, v1 = 0.f, v2 = 0.f, v3 = 0.f;
#pragma unroll
    for (int kq = 0; kq < 8; ++kq) {
      v0 += p[PIDX(kq, t2, 0, r)];
      v1 += p[PIDX(kq, t2, 1, r)];
      v2 += p[PIDX(kq, t2, 2, r)];
      v3 += p[PIDX(kq, t2, 3, r)];
    }

    const int tok = tokBase + t2 * 16 + (l >> 4) * 4 + r;
    {
      float* dst = out_lg + (size_t)tok * NEXP + (l & 15);
      dst[0]  = v0;
      dst[16] = v1;
      dst[32] = v2;
      dst[48] = v3;
    }

    const int cbase = (l & 15);
    int i0 = cbase, i1 = cbase + 16, i2 = cbase + 32, i3 = cbase + 48;
    CE(v0, i0, v1, i1) CE(v2, i2, v3, i3) CE(v0, i0, v2, i2) CE(v1, i1, v3, i3) CE(v1, i1, v2, i2)
#pragma unroll
    for (int m = 1; m <= 8; m <<= 1) {
      float p0 = __shfl_xor(v0, m), p1 = __shfl_xor(v1, m);
      float p2 = __shfl_xor(v2, m), p3 = __shfl_xor(v3, m);
      int j0 = __shfl_xor(i0, m), j1 = __shfl_xor(i1, m);
      int j2 = __shfl_xor(i2, m), j3 = __shfl_xor(i3, m);
      CE(v0, i0, p3, j3) CE(v1, i1, p2, j2) CE(v2, i2, p1, j1) CE(v3, i3, p0, j0)
      CE(v0, i0, v2, i2) CE(v1, i1, v3, i3) CE(v0, i0, v1, i1) CE(v2, i2, v3, i3)
    }

    bool flag = false;
    unsigned pk = 0;
    if (cbase == 0) {
      flag = (v0 - v1 < TAU) || (v1 - v2 < TAU) || (v2 - v3 < TAU);
      pk = (unsigned)i0 | ((unsigned)i1 << 8) | ((unsigned)i2 << 16) | ((unsigned)i3 << 24);
      if (!flag) {
        float ex = expf(v1 - v0);
        float den = 1.0f + ex;
        out_idx[tok * 2 + 0] = (float)i0;
        out_idx[tok * 2 + 1] = (float)i1;
        out_wt[tok * 2 + 0]  = 1.0f / den;
        out_wt[tok * 2 + 1]  = ex / den;
      }
    }
    unsigned long long mk = __ballot(flag);
    while (mk) {
      const int src = __builtin_ctzll(mk);
      mk &= mk - 1;
      const unsigned pks = (unsigned)__shfl((int)pk, src);
      fixup_token(x, wgt, out_idx, out_wt, tokBase + t2 * 16 + (src >> 4) * 4 + r, pks, l);
    }
  }
}

extern "C" void kernel_launch(void* const* d_in, const int* in_sizes, int n_in,
                              void* d_out, int out_size, void* d_ws, size_t ws_size,
                              hipStream_t stream) {
  const float* x = (const float*)d_in[0];   // [4,4096,4096] f32
  const float* w = (const float*)d_in[1];   // [64,4096] f32
  float* out = (float*)d_out;               // 32768 idx + 32768 wt + 1048576 logits (all f32)
  short* ws = (short*)d_ws;                 // 1 MiB: bf16 hi/lo planes of W

  hipLaunchKernelGGL(presplit_w, dim3(128), dim3(256), 0, stream, w, ws);
  hipLaunchKernelGGL(router_main, dim3(NTOK / 32), dim3(512), 0, stream, x, w, ws, out);
}

// Round 12
// 85.217 us; speedup vs baseline: 1.0737x; 1.0737x over previous
//
#include <hip/hip_runtime.h>
#include <math.h>

#define NTOK 16384
#define DDIM 4096
#define NEXP 64
#define TAU  2e-4f
#define WS_LO 262144   // short-offset of the lo-plane inside d_ws
#define NCW  16        // chunks per K-eighth (512 k / 32)

typedef short bf16x8 __attribute__((ext_vector_type(8)));
typedef float f32x4  __attribute__((ext_vector_type(4)));

__device__ __forceinline__ unsigned short bf16_rne(float f) {
  unsigned u = __float_as_uint(f);
  u += 0x7fffu + ((u >> 16) & 1u);
  return (unsigned short)(u >> 16);
}

__device__ __forceinline__ void split4(float4 v, uint2& hi, uint2& lo) {
  unsigned h0 = bf16_rne(v.x), h1 = bf16_rne(v.y), h2 = bf16_rne(v.z), h3 = bf16_rne(v.w);
  float r0 = v.x - __uint_as_float(h0 << 16);
  float r1 = v.y - __uint_as_float(h1 << 16);
  float r2 = v.z - __uint_as_float(h2 << 16);
  float r3 = v.w - __uint_as_float(h3 << 16);
  unsigned l0 = bf16_rne(r0), l1 = bf16_rne(r1), l2 = bf16_rne(r2), l3 = bf16_rne(r3);
  hi = make_uint2(h0 | (h1 << 16), h2 | (h3 << 16));
  lo = make_uint2(l0 | (l1 << 16), l2 | (l3 << 16));
}

__device__ __forceinline__ void split4v(f32x4 v, uint2& hi, uint2& lo) {
  unsigned h0 = bf16_rne(v[0]), h1 = bf16_rne(v[1]), h2 = bf16_rne(v[2]), h3 = bf16_rne(v[3]);
  float r0 = v[0] - __uint_as_float(h0 << 16);
  float r1 = v[1] - __uint_as_float(h1 << 16);
  float r2 = v[2] - __uint_as_float(h2 << 16);
  float r3 = v[3] - __uint_as_float(h3 << 16);
  unsigned l0 = bf16_rne(r0), l1 = bf16_rne(r1), l2 = bf16_rne(r2), l3 = bf16_rne(r3);
  hi = make_uint2(h0 | (h1 << 16), h2 | (h3 << 16));
  lo = make_uint2(l0 | (l1 << 16), l2 | (l3 << 16));
}

__device__ __forceinline__ bf16x8 mk8(uint2 a, uint2 b) {
  union { uint4 u; bf16x8 v; } t;
  t.u = make_uint4(a.x, a.y, b.x, b.y);
  return t.v;
}

__device__ __forceinline__ void gld_lds16(const float* g, char* l) {
  __builtin_amdgcn_global_load_lds((const __attribute__((address_space(1))) void*)g,
                                   (__attribute__((address_space(3))) void*)l,
                                   16, 0, 0);
}

__device__ __forceinline__ bool better(float va, int ia, float vb, int ib) {
  return (va > vb) || (va == vb && ia < ib);
}
__device__ __forceinline__ bool betterd(double va, int ia, double vb, int ib) {
  return (va > vb) || (va == vb && ia < ib);
}
#define CE(va, ia, vb, ib) { if (better(vb, ib, va, ia)) { float _tv = va; va = vb; vb = _tv; int _ti = ia; ia = ib; ib = _ti; } }

// ---- kernel 1: split W (fp32) into bf16 hi/lo, MFMA-fragment-linear, once ----
__global__ __launch_bounds__(256)
void presplit_w(const float* __restrict__ w, short* __restrict__ ws) {
  const int tid = blockIdx.x * 256 + threadIdx.x;  // 32768 threads
  const int e = tid >> 9;          // expert 0..63
  const int o = tid & 511;         // k-octet 0..511
  const int c = o >> 2, q = o & 3;
  const int l = (e & 15) + 16 * q;
  const int g = e >> 4;
  const float* src = w + (size_t)e * DDIM + o * 8;
  float4 v0 = *(const float4*)src;
  float4 v1 = *(const float4*)(src + 4);
  uint2 h0, s0, h1, s1;
  split4(v0, h0, s0);
  split4(v1, h1, s1);
  const int off = c * 2048 + g * 512 + l * 8;
  *(uint4*)(ws + off)         = make_uint4(h0.x, h0.y, h1.x, h1.y);
  *(uint4*)(ws + WS_LO + off) = make_uint4(s0.x, s0.y, s1.x, s1.y);
}

// ---- fp64 recompute for near-tie tokens (rare); executed by one full wave ----
__device__ __noinline__ void fixup_token(const float* __restrict__ x,
                                         const float* __restrict__ wgt,
                                         float* __restrict__ out_idx,
                                         float* __restrict__ out_wt,
                                         int tok, unsigned pk, int l) {
  const int e0 = pk & 255, e1 = (pk >> 8) & 255, e2 = (pk >> 16) & 255, e3 = (pk >> 24) & 255;
  const float* xr = x   + (size_t)tok * DDIM + l * 64;
  const float* w0 = wgt + (size_t)e0 * DDIM + l * 64;
  const float* w1 = wgt + (size_t)e1 * DDIM + l * 64;
  const float* w2 = wgt + (size_t)e2 * DDIM + l * 64;
  const float* w3 = wgt + (size_t)e3 * DDIM + l * 64;
  double s0 = 0.0, s1 = 0.0, s2 = 0.0, s3 = 0.0;
#pragma unroll 4
  for (int j = 0; j < 64; j += 4) {
    float4 xv = *(const float4*)(xr + j);
    float4 av = *(const float4*)(w0 + j);
    s0 = fma((double)xv.x, (double)av.x, s0); s0 = fma((double)xv.y, (double)av.y, s0);
    s0 = fma((double)xv.z, (double)av.z, s0); s0 = fma((double)xv.w, (double)av.w, s0);
    av = *(const float4*)(w1 + j);
    s1 = fma((double)xv.x, (double)av.x, s1); s1 = fma((double)xv.y, (double)av.y, s1);
    s1 = fma((double)xv.z, (double)av.z, s1); s1 = fma((double)xv.w, (double)av.w, s1);
    av = *(const float4*)(w2 + j);
    s2 = fma((double)xv.x, (double)av.x, s2); s2 = fma((double)xv.y, (double)av.y, s2);
    s2 = fma((double)xv.z, (double)av.z, s2); s2 = fma((double)xv.w, (double)av.w, s2);
    av = *(const float4*)(w3 + j);
    s3 = fma((double)xv.x, (double)av.x, s3); s3 = fma((double)xv.y, (double)av.y, s3);
    s3 = fma((double)xv.z, (double)av.z, s3); s3 = fma((double)xv.w, (double)av.w, s3);
  }
#pragma unroll
  for (int m = 1; m < 64; m <<= 1) {
    s0 += __shfl_xor(s0, m);
    s1 += __shfl_xor(s1, m);
    s2 += __shfl_xor(s2, m);
    s3 += __shfl_xor(s3, m);
  }
  if (l == 0) {
    double v0 = s0, v1 = s1, v2 = s2, v3 = s3;
    int i0 = e0, i1 = e1, i2 = e2, i3 = e3;
    if (betterd(v1, i1, v0, i0)) { double tv = v0; v0 = v1; v1 = tv; int ti = i0; i0 = i1; i1 = ti; }
    if (betterd(v3, i3, v2, i2)) { double tv = v2; v2 = v3; v3 = tv; int ti = i2; i2 = i3; i3 = ti; }
    if (betterd(v2, i2, v0, i0)) { double tv = v0; v0 = v2; v2 = tv; int ti = i0; i0 = i2; i2 = ti; }
    if (betterd(v3, i3, v1, i1)) { double tv = v1; v1 = v3; v3 = tv; int ti = i1; i1 = i3; i3 = ti; }
    if (betterd(v2, i2, v1, i1)) { double tv = v1; v1 = v2; v2 = tv; int ti = i1; i1 = i2; i2 = ti; }
    double ex = exp(v1 - v0);
    double den = 1.0 + ex;
    out_idx[tok * 2 + 0] = (float)i0;
    out_idx[tok * 2 + 1] = (float)i1;
    out_wt[tok * 2 + 0]  = (float)(1.0 / den);
    out_wt[tok * 2 + 1]  = (float)(ex / den);
  }
}

// ---- kernel 2: K-split x8, W single-buffered => VGPR<=128 => 16 waves/CU ----
// 512 blocks x 512 thr (8 waves = 8 K-eighths). Block = 32 tokens x 64 experts.
// Per step: vmcnt(4) [X(T),W(T) landed; X(T+1) airborne]; ds_read; split;
// MM g0,g1; reload wset[0..3]=W(T+1); MM g2,g3; reload wset[4..7]; XISSUE(T+2).
// LDS 64 KB/block, VGPR cap 128 -> 2 blocks/CU = 16 waves/CU.
__global__ __launch_bounds__(512, 4)
void router_main(const float* __restrict__ x, const float* __restrict__ wgt,
                 const short* __restrict__ ws, float* __restrict__ out) {
  __shared__ __align__(16) char ldsbuf[65536];

  const int u = threadIdx.x;
  const int l = u & 63;
  const int wid = u >> 6;          // K-eighth 0..7
  const int tokBase = blockIdx.x * 32;

  char* ring = ldsbuf + wid * 8192;   // 2 slots x 4096 B
  const unsigned ldsbase =
      (unsigned)(size_t)(__attribute__((address_space(3))) char*)&ldsbuf[0];
  const unsigned rbase = ldsbase + wid * 8192 + l * 16;

  // k-phase rotation across blocks (within this wave's 16 chunks)
  const int P = (blockIdx.x * 5) & 15;
#define PHYS(T) (((T) + P) & 15)

  // A-fragment sources per token-tile: lane l = row (l&15), k-oct (l>>4)*8
  const float* xA0 = x + (size_t)(tokBase +  0 + (l & 15)) * DDIM + wid * 512 + (l >> 4) * 8;
  const float* xA1 = x + (size_t)(tokBase + 16 + (l & 15)) * DDIM + wid * 512 + (l >> 4) * 8;

  const short* wch = ws + wid * 32768 + l * 8;

  f32x4 acc[2][4];   // [token-tile][expert-group], all indices compile-time
#pragma unroll
  for (int t2 = 0; t2 < 2; ++t2)
#pragma unroll
    for (int g = 0; g < 4; ++g) acc[t2][g] = (f32x4){0.f, 0.f, 0.f, 0.f};

  bf16x8 wset[8];    // single-buffered

#define LDW_A(T)                                                               \
  { const int cw_ = ((T) < NCW) ? (T) : NCW - 1;                               \
    const int cc_ = PHYS(cw_);                                                 \
    asm volatile("" ::: "memory");                                             \
    wset[0] = *(const bf16x8*)(wch + cc_ * 2048 + 0 * 512);                    \
    wset[1] = *(const bf16x8*)(wch + WS_LO + cc_ * 2048 + 0 * 512);            \
    wset[2] = *(const bf16x8*)(wch + cc_ * 2048 + 1 * 512);                    \
    wset[3] = *(const bf16x8*)(wch + WS_LO + cc_ * 2048 + 1 * 512);            \
    asm volatile("" ::: "memory"); }

#define LDW_B(T)                                                               \
  { const int cw_ = ((T) < NCW) ? (T) : NCW - 1;                               \
    const int cc_ = PHYS(cw_);                                                 \
    asm volatile("" ::: "memory");                                             \
    wset[4] = *(const bf16x8*)(wch + cc_ * 2048 + 2 * 512);                    \
    wset[5] = *(const bf16x8*)(wch + WS_LO + cc_ * 2048 + 2 * 512);            \
    wset[6] = *(const bf16x8*)(wch + cc_ * 2048 + 3 * 512);                    \
    wset[7] = *(const bf16x8*)(wch + WS_LO + cc_ * 2048 + 3 * 512);            \
    asm volatile("" ::: "memory"); }

#define XISSUE(T, SLOT)                                                        \
  { const int cx_ = ((T) < NCW) ? (T) : NCW - 1;                               \
    const int cp_ = PHYS(cx_) * 32;                                            \
    char* d_ = ring + (SLOT) * 4096;                                           \
    gld_lds16(xA0 + cp_, d_);                                                  \
    gld_lds16(xA0 + cp_ + 4, d_ + 1024);                                       \
    gld_lds16(xA1 + cp_, d_ + 2048);                                           \
    gld_lds16(xA1 + cp_ + 4, d_ + 3072); }

#define MM(T2, G, AHI, ALO)                                                    \
  acc[T2][G] = __builtin_amdgcn_mfma_f32_16x16x32_bf16(AHI, wset[2*(G)],   acc[T2][G], 0, 0, 0); \
  acc[T2][G] = __builtin_amdgcn_mfma_f32_16x16x32_bf16(AHI, wset[2*(G)+1], acc[T2][G], 0, 0, 0); \
  acc[T2][G] = __builtin_amdgcn_mfma_f32_16x16x32_bf16(ALO, wset[2*(G)],   acc[T2][G], 0, 0, 0);

// per step T (consume X slot T&1 and wset=W(T)):
#define STEP(T)                                                                \
  {                                                                            \
    asm volatile("s_waitcnt vmcnt(4)" ::: "memory");                           \
    f32x4 f0, f1, f2, f3;                                                      \
    { unsigned a_ = rbase + ((T) & 1) * 4096;                                  \
      asm volatile("ds_read_b128 %0, %2\n\tds_read_b128 %1, %2 offset:1024"    \
                   : "=&v"(f0), "=&v"(f1) : "v"(a_));                          \
      asm volatile("ds_read_b128 %0, %2 offset:2048\n\tds_read_b128 %1, %2 offset:3072" \
                   : "=&v"(f2), "=&v"(f3) : "v"(a_)); }                        \
    asm volatile("s_waitcnt lgkmcnt(0)" ::: "memory");                         \
    __builtin_amdgcn_sched_barrier(0);                                         \
    uint2 h0_, s0_, h1_, s1_;                                                  \
    split4v(f0, h0_, s0_); split4v(f1, h1_, s1_);                              \
    bf16x8 a0hi = mk8(h0_, h1_), a0lo = mk8(s0_, s1_);                         \
    split4v(f2, h0_, s0_); split4v(f3, h1_, s1_);                              \
    bf16x8 a1hi = mk8(h0_, h1_), a1lo = mk8(s0_, s1_);                         \
    MM(0, 0, a0hi, a0lo) MM(0, 1, a0hi, a0lo)                                  \
    MM(1, 0, a1hi, a1lo) MM(1, 1, a1hi, a1lo)                                  \
    LDW_A((T) + 1)                                                             \
    MM(0, 2, a0hi, a0lo) MM(0, 3, a0hi, a0lo)                                  \
    MM(1, 2, a1hi, a1lo) MM(1, 3, a1hi, a1lo)                                  \
    LDW_B((T) + 1)                                                             \
    XISSUE((T) + 2, (T) & 1)                                                   \
  }

  // prologue FIFO: X0(4), W0(8), X1(4) = 16 outstanding
  XISSUE(0, 0)
  LDW_A(0) LDW_B(0)
  XISSUE(1, 1)

#pragma unroll
  for (int t = 0; t < NCW; ++t) {
    STEP(t)
  }

  // ---- combine K-eighths through LDS (aliased over the rings, 64 KB exactly) ----
  __syncthreads();   // drains vmcnt(0): all dead gld_lds landed; rings dead
  float* p = (float*)ldsbuf;
#define PIDX(KQ, T2, G, R) ((((((KQ) * 2 + (T2)) * 4 + (G)) * 4 + (R)) << 6) + l)
#pragma unroll
  for (int t2 = 0; t2 < 2; ++t2)
#pragma unroll
    for (int g = 0; g < 4; ++g)
#pragma unroll
      for (int r = 0; r < 4; ++r)
        p[PIDX(wid, t2, g, r)] = acc[t2][g][r];
  __syncthreads();

  float* out_idx = out;
  float* out_wt  = out + NTOK * 2;
  float* out_lg  = out + NTOK * 4;

  // wave `wid` handles (t2 = wid>>2, r = wid&3): tokens t2*16 + (l>>4)*4 + r
  {
    const int t2 = wid >> 2;
    const int r  = wid & 3;
    float v0 = 0.f, v1 = 0.f, v2 = 0.f, v3 = 0.f;
#pragma unroll
    for (int kq = 0; kq < 8; ++kq) {
      v0 += p[PIDX(kq, t2, 0, r)];
      v1 += p[PIDX(kq, t2, 1, r)];
      v2 += p[PIDX(kq, t2, 2, r)];
      v3 += p[PIDX(kq, t2, 3, r)];
    }

    const int tok = tokBase + t2 * 16 + (l >> 4) * 4 + r;
    {
      float* dst = out_lg + (size_t)tok * NEXP + (l & 15);
      dst[0]  = v0;
      dst[16] = v1;
      dst[32] = v2;
      dst[48] = v3;
    }

    const int cbase = (l & 15);
    int i0 = cbase, i1 = cbase + 16, i2 = cbase + 32, i3 = cbase + 48;
    CE(v0, i0, v1, i1) CE(v2, i2, v3, i3) CE(v0, i0, v2, i2) CE(v1, i1, v3, i3) CE(v1, i1, v2, i2)
#pragma unroll
    for (int m = 1; m <= 8; m <<= 1) {
      float p0 = __shfl_xor(v0, m), p1 = __shfl_xor(v1, m);
      float p2 = __shfl_xor(v2, m), p3 = __shfl_xor(v3, m);
      int j0 = __shfl_xor(i0, m), j1 = __shfl_xor(i1, m);
      int j2 = __shfl_xor(i2, m), j3 = __shfl_xor(i3, m);
      CE(v0, i0, p3, j3) CE(v1, i1, p2, j2) CE(v2, i2, p1, j1) CE(v3, i3, p0, j0)
      CE(v0, i0, v2, i2) CE(v1, i1, v3, i3) CE(v0, i0, v1, i1) CE(v2, i2, v3, i3)
    }

    bool flag = false;
    unsigned pk = 0;
    if (cbase == 0) {
      flag = (v0 - v1 < TAU) || (v1 - v2 < TAU) || (v2 - v3 < TAU);
      pk = (unsigned)i0 | ((unsigned)i1 << 8) | ((unsigned)i2 << 16) | ((unsigned)i3 << 24);
      if (!flag) {
        float ex = expf(v1 - v0);
        float den = 1.0f + ex;
        out_idx[tok * 2 + 0] = (float)i0;
        out_idx[tok * 2 + 1] = (float)i1;
        out_wt[tok * 2 + 0]  = 1.0f / den;
        out_wt[tok * 2 + 1]  = ex / den;
      }
    }
    unsigned long long mk = __ballot(flag);
    while (mk) {
      const int src = __builtin_ctzll(mk);
      mk &= mk - 1;
      const unsigned pks = (unsigned)__shfl((int)pk, src);
      fixup_token(x, wgt, out_idx, out_wt, tokBase + t2 * 16 + (src >> 4) * 4 + r, pks, l);
    }
  }
}

extern "C" void kernel_launch(void* const* d_in, const int* in_sizes, int n_in,
                              void* d_out, int out_size, void* d_ws, size_t ws_size,
                              hipStream_t stream) {
  const float* x = (const float*)d_in[0];   // [4,4096,4096] f32
  const float* w = (const float*)d_in[1];   // [64,4096] f32
  float* out = (float*)d_out;               // 32768 idx + 32768 wt + 1048576 logits (all f32)
  short* ws = (short*)d_ws;                 // 1 MiB: bf16 hi/lo planes of W

  hipLaunchKernelGGL(presplit_w, dim3(128), dim3(256), 0, stream, w, ws);
  hipLaunchKernelGGL(router_main, dim3(NTOK / 32), dim3(512), 0, stream, x, w, ws, out);
}